// Round 22
// baseline (55.285 us; speedup 1.0000x reference)
//
#include <hip/hip_runtime.h>
#include <math.h>
#include <stdint.h>

#define EMBED 512
#define HID 16
#define SEQ 1024

typedef unsigned short u16;
typedef __attribute__((ext_vector_type(8))) __bf16 bf16x8;
typedef __attribute__((ext_vector_type(4))) float f32x4;

__device__ __forceinline__ u16 f2bf(float f) {
    unsigned u = __float_as_uint(f);
    unsigned r = (u + 0x7FFFu + ((u >> 16) & 1u)) >> 16;   // RNE
    return (u16)r;
}
__device__ __forceinline__ float bf2f(u16 h) {
    return __uint_as_float(((unsigned)h) << 16);
}
__device__ __forceinline__ void gload16(const void* g, void* d) {
    __builtin_amdgcn_global_load_lds(
        reinterpret_cast<const __attribute__((address_space(1))) unsigned int*>(
            reinterpret_cast<uintptr_t>(g)),
        reinterpret_cast<__attribute__((address_space(3))) unsigned int*>(
            reinterpret_cast<uintptr_t>(d)),
        16, 0, 0);
}

// ---------------- Kernel 1: prep — fold Wc rows + Wv split + x split ----------------
// A-matrix rows 0..511 = Wv hi/lo; 512..543 = Wc hi/lo; 544..575 = zero pad.
__global__ __launch_bounds__(256) void prep_kernel(
    const float* __restrict__ Wq, const float* __restrict__ Wk,
    const float* __restrict__ W1, const float* __restrict__ Wvm,
    const float* __restrict__ x,
    u16* __restrict__ AH, u16* __restrict__ AL, u16* __restrict__ x_hi)
{
    __shared__ float w1s[EMBED];
    int t = threadIdx.x;
    int blk = blockIdx.x;
    if (blk < 64) {
        int h2 = blk >> 1, half = blk & 1;
        int ab = h2 >> 4, h = h2 & 15;
        const float* Wmat = ab ? Wk : Wq;
        const float* w1row = W1 + (size_t)h * (2 * EMBED) + ab * EMBED;
        for (int f = t; f < EMBED; f += 256) w1s[f] = w1row[f];
        __syncthreads();
        int e0 = (half << 8) + t;
        float acc = 0.f;
        #pragma unroll 16
        for (int f = 0; f < EMBED; ++f)
            acc += w1s[f] * Wmat[(size_t)f * EMBED + e0];
        u16 hi = f2bf(acc);
        AH[(size_t)(512 + h2) * EMBED + e0] = hi;
        AL[(size_t)(512 + h2) * EMBED + e0] = f2bf(acc - bf2f(hi));
        AH[(size_t)(544 + h2) * EMBED + e0] = 0;        // pad rows 544..575
        AL[(size_t)(544 + h2) * EMBED + e0] = 0;
    } else if (blk < 320) {
        int i = (blk - 64) * 256 + t;                   // float4 idx < 65536
        float4 v = ((const float4*)Wvm)[i];
        u16 h0 = f2bf(v.x), h1 = f2bf(v.y), h2 = f2bf(v.z), h3 = f2bf(v.w);
        ((ushort4*)AH)[i] = make_ushort4(h0, h1, h2, h3);
        ((ushort4*)AL)[i] = make_ushort4(f2bf(v.x - bf2f(h0)), f2bf(v.y - bf2f(h1)),
                                         f2bf(v.z - bf2f(h2)), f2bf(v.w - bf2f(h3)));
    } else {
        int i = (blk - 320) * 256 + t;                  // float4 idx < 524288
        float4 v = ((const float4*)x)[i];
        ((ushort4*)x_hi)[i] = make_ushort4(f2bf(v.x), f2bf(v.y), f2bf(v.z), f2bf(v.w));
    }
}

// ---------------- staging helpers (128B-row tiles, XOR swizzle; proven) ----------------
template<int NR>
__device__ __forceinline__ void stageR(const u16* src, int ld, int kt,
                                       u16* ldsb, int t)
{
    int kb0 = kt << 7;
    #pragma unroll
    for (int i = 0; i < NR / 32; ++i) {
        int row  = i * 32 + (t >> 3);
        int colb = (((t & 7) ^ ((t >> 3) & 7)) << 4);
        const char* g = (const char*)src + (size_t)row * ((size_t)ld * 2) + kb0 + colb;
        gload16(g, (char*)ldsb + i * 4096 + ((t >> 6) << 10) + ((t & 63) << 4));
    }
}
__device__ __forceinline__ bf16x8 ldfrag(const u16* ldsb, int r, int s) {
    return *(const bf16x8*)((const char*)ldsb + r * 128 + (((s ^ (r & 7))) << 4));
}

// ---------------- Kernel 2: unified GEMM  [Wv;Wc;pad] x x_hi^T (64x64 tile) ---------
// M=576, N=4096, K=512. Single-term m-tiles (Wv): PAIR-DOUBLE-BUFFERED
// (2 K-tiles/round, prefetch next pair during MFMA -> stage drain off critical
// path; 64 KB LDS, 2 blocks/CU). Two-term Wc tile (1/9, off critical path):
// proven pair-single inside the same alloc. XCD-swizzled. Sum order unchanged.
__global__ __launch_bounds__(256, 2) void gemm_kernel(
    const u16* __restrict__ AH, const u16* __restrict__ AL,
    const u16* __restrict__ Bh, const float* __restrict__ b1,
    u16* __restrict__ VT, float* __restrict__ EAt, float* __restrict__ EBt)
{
    const float K2 = 2.8853900817779268f;   // 2*log2(e)
    __shared__ __attribute__((aligned(16))) u16 lds[32768];   // 64 KB
    int t = threadIdx.x;
    int l = t & 63, wid = t >> 6;
    int wm = (wid >> 1) * 32, wn = (wid & 1) * 32;
    // bijective XCD swizzle: 576 = 8 XCD-chunks x 72 (8 n-tiles x 9 m-tiles)
    int lin = blockIdx.y * 64 + blockIdx.x;
    int v = (lin & 7) * 72 + (lin >> 3);
    int mt = v % 9, nt = v / 9;
    int m0 = mt * 64, n0 = nt * 64;
    const u16* pAh = AH + (size_t)m0 * EMBED;
    const u16* pAl = AL + (size_t)m0 * EMBED;
    const u16* pBh = Bh + (size_t)n0 * EMBED;
    f32x4 acc[2][2] = {};
    const bool two = (mt == 8);     // Wc tile: 2-term

    if (two) {
        // pair-single 2-term path (R19-proven; uses 48 KB of the alloc)
        for (int kp = 0; kp < 4; ++kp) {
            stageR<64>(pAh, EMBED, 2 * kp,     lds,         t);
            stageR<64>(pAl, EMBED, 2 * kp,     lds + 4096,  t);
            stageR<64>(pBh, EMBED, 2 * kp,     lds + 8192,  t);
            stageR<64>(pAh, EMBED, 2 * kp + 1, lds + 12288, t);
            stageR<64>(pAl, EMBED, 2 * kp + 1, lds + 16384, t);
            stageR<64>(pBh, EMBED, 2 * kp + 1, lds + 20480, t);
            __syncthreads();
            #pragma unroll
            for (int half = 0; half < 2; ++half) {
                u16* lAh = lds + half * 12288;
                u16* lAl = lAh + 4096;
                u16* lB  = lAh + 8192;
                #pragma unroll
                for (int kk = 0; kk < 2; ++kk) {
                    int sb = (kk << 2) + (l >> 4);
                    bf16x8 ah[2], al2[2], bh[2];
                    #pragma unroll
                    for (int mf = 0; mf < 2; ++mf) {
                        ah[mf]  = ldfrag(lAh, wm + mf * 16 + (l & 15), sb);
                        al2[mf] = ldfrag(lAl, wm + mf * 16 + (l & 15), sb);
                    }
                    #pragma unroll
                    for (int nf = 0; nf < 2; ++nf)
                        bh[nf] = ldfrag(lB, wn + nf * 16 + (l & 15), sb);
                    #pragma unroll
                    for (int mf = 0; mf < 2; ++mf)
                        #pragma unroll
                        for (int nf = 0; nf < 2; ++nf) {
                            acc[mf][nf] = __builtin_amdgcn_mfma_f32_16x16x32_bf16(ah[mf],  bh[nf], acc[mf][nf], 0, 0, 0);
                            acc[mf][nf] = __builtin_amdgcn_mfma_f32_16x16x32_bf16(al2[mf], bh[nf], acc[mf][nf], 0, 0, 0);
                        }
                }
            }
            __syncthreads();
        }
    } else {
        // single-term PAIR-DBUF path: buf b at b*16384; within buf:
        // tile half h: A at h*8192, B at h*8192+4096.
        auto STAGE = [&](int buf, int kp) {
            u16* base = lds + buf * 16384;
            stageR<64>(pAh, EMBED, 2 * kp,     base,         t);
            stageR<64>(pBh, EMBED, 2 * kp,     base + 4096,  t);
            stageR<64>(pAh, EMBED, 2 * kp + 1, base + 8192,  t);
            stageR<64>(pBh, EMBED, 2 * kp + 1, base + 12288, t);
        };
        auto COMPUTE = [&](int buf) {
            #pragma unroll
            for (int half = 0; half < 2; ++half) {
                u16* lA = lds + buf * 16384 + half * 8192;
                u16* lB = lA + 4096;
                #pragma unroll
                for (int kk = 0; kk < 2; ++kk) {
                    int sb = (kk << 2) + (l >> 4);
                    bf16x8 ah[2], bh[2];
                    #pragma unroll
                    for (int mf = 0; mf < 2; ++mf)
                        ah[mf] = ldfrag(lA, wm + mf * 16 + (l & 15), sb);
                    #pragma unroll
                    for (int nf = 0; nf < 2; ++nf)
                        bh[nf] = ldfrag(lB, wn + nf * 16 + (l & 15), sb);
                    #pragma unroll
                    for (int mf = 0; mf < 2; ++mf)
                        #pragma unroll
                        for (int nf = 0; nf < 2; ++nf)
                            acc[mf][nf] = __builtin_amdgcn_mfma_f32_16x16x32_bf16(ah[mf], bh[nf], acc[mf][nf], 0, 0, 0);
                }
            }
        };
        STAGE(0, 0);
        __syncthreads();
        int cur = 0;
        for (int kp = 0; kp + 1 < 4; ++kp) {
            STAGE(cur ^ 1, kp + 1);     // prefetch next pair during compute
            COMPUTE(cur);
            __syncthreads();
            cur ^= 1;
        }
        COMPUTE(cur);
    }

    int cr = (l >> 4) << 2, cc = l & 15;
    #pragma unroll
    for (int mf = 0; mf < 2; ++mf)
        #pragma unroll
        for (int nf = 0; nf < 2; ++nf)
            #pragma unroll
            for (int r = 0; r < 4; ++r) {
                int gr = m0 + wm + mf * 16 + cr + r;
                int col = n0 + wn + nf * 16 + cc;
                float v2 = acc[mf][nf][r];
                if (gr < 512) {
                    VT[(size_t)gr * 4096 + col] = f2bf(v2);
                } else if (gr < 528) {
                    EAt[(size_t)(gr - 512) * 4096 + col] =
                        __builtin_amdgcn_exp2f(K2 * (v2 + b1[gr - 512]));
                } else if (gr < 544) {
                    EBt[(size_t)(gr - 528) * 4096 + col] =
                        __builtin_amdgcn_exp2f(K2 * v2);
                }
            }
}

// ---------------- Kernel 3: logits + fixed-max softmax -> P (bf16, normalized) -------
// 4 q-rows/block (grid 1024): EB L2 traffic halves. Per-row sum order identical.
__global__ __launch_bounds__(256) void attn_kernel(
    const float* __restrict__ EAt, const float* __restrict__ EBt,
    const float* __restrict__ w2, u16* __restrict__ P)
{
    const float L2E = 1.4426950408889634f;
    __shared__ float redA[4], redB[4], redC[4], redD[4];
    int blk = blockIdx.x;             // 0..1023
    int b = blk >> 8;
    int i0 = (blk & 255) << 2;        // 4 rows per block
    int t = threadIdx.x;
    int gA = (b << 10) + i0;

    float ax[HID], ay[HID], az[HID], aw[HID];
    #pragma unroll
    for (int h = 0; h < HID; ++h) {
        const float* Er = EAt + (size_t)h * 4096 + gA;
        ax[h] = Er[0]; ay[h] = Er[1]; az[h] = Er[2]; aw[h] = Er[3];
    }

    float P1a[8], P2a[8], PSa[8];
    #pragma unroll
    for (int p = 0; p < 8; ++p) {
        float w1 = -2.f * w2[2 * p], w2_ = -2.f * w2[2 * p + 1];
        P1a[p] = w1; P2a[p] = w2_; PSa[p] = w1 + w2_;
    }
    float S0 = 0.f;
    #pragma unroll
    for (int p = 0; p < 8; ++p) S0 += fmaxf(P1a[p], 0.f) + fmaxf(P2a[p], 0.f);

    const float* EBb = EBt + (b << 10);
    float pa0, pa1, pa2, pa3, pb0, pb1, pb2, pb3;
    float pc0, pc1, pc2, pc3, pd0, pd1, pd2, pd3;

#define ROWSUM(S, AV) { \
    _Pragma("unroll") \
    for (int q = 0; q < 4; ++q) { \
        int h0 = q << 2, p0 = q << 1, p1 = p0 + 1; \
        float e1 = AV[h0]*bb[h0], e2 = AV[h0+1]*bb[h0+1]; \
        float e3 = AV[h0+2]*bb[h0+2], e4 = AV[h0+3]*bb[h0+3]; \
        float D12 = fmaf(e1, e2, e1) + (e2 + 1.0f); \
        float N12 = fmaf(P2a[p0], e1, fmaf(P1a[p0], e2, PSa[p0])); \
        float D34 = fmaf(e3, e4, e3) + (e4 + 1.0f); \
        float N34 = fmaf(P2a[p1], e3, fmaf(P1a[p1], e4, PSa[p1])); \
        S = fmaf(fmaf(N12, D34, N34 * D12), __builtin_amdgcn_rcpf(D12 * D34), S); \
    } }

#define DOC(c, PA, PB, PC, PD) { \
    int j = t + (c) * 256; \
    float bb[HID]; \
    _Pragma("unroll") \
    for (int h = 0; h < HID; ++h) bb[h] = EBb[(size_t)h * 4096 + j]; \
    float sA = 0.f, sB = 0.f, sC = 0.f, sD = 0.f; \
    ROWSUM(sA, ax) ROWSUM(sB, ay) ROWSUM(sC, az) ROWSUM(sD, aw) \
    PA = __builtin_amdgcn_exp2f((sA - S0) * L2E); \
    PB = __builtin_amdgcn_exp2f((sB - S0) * L2E); \
    PC = __builtin_amdgcn_exp2f((sC - S0) * L2E); \
    PD = __builtin_amdgcn_exp2f((sD - S0) * L2E); }

    DOC(0, pa0, pb0, pc0, pd0)
    DOC(1, pa1, pb1, pc1, pd1)
    DOC(2, pa2, pb2, pc2, pd2)
    DOC(3, pa3, pb3, pc3, pd3)
#undef DOC
#undef ROWSUM

    float sA = (pa0 + pa1) + (pa2 + pa3);
    float sB = (pb0 + pb1) + (pb2 + pb3);
    float sC = (pc0 + pc1) + (pc2 + pc3);
    float sD = (pd0 + pd1) + (pd2 + pd3);
    #pragma unroll
    for (int o = 32; o > 0; o >>= 1) {
        sA += __shfl_xor(sA, o);
        sB += __shfl_xor(sB, o);
        sC += __shfl_xor(sC, o);
        sD += __shfl_xor(sD, o);
    }
    if ((t & 63) == 0) {
        redA[t >> 6] = sA; redB[t >> 6] = sB;
        redC[t >> 6] = sC; redD[t >> 6] = sD;
    }
    __syncthreads();
    float invA = __fdividef(1.f, (redA[0] + redA[1]) + (redA[2] + redA[3]));
    float invB = __fdividef(1.f, (redB[0] + redB[1]) + (redB[2] + redB[3]));
    float invC = __fdividef(1.f, (redC[0] + redC[1]) + (redC[2] + redC[3]));
    float invD = __fdividef(1.f, (redD[0] + redD[1]) + (redD[2] + redD[3]));

    size_t baseA = ((size_t)(b * SEQ) + i0) * SEQ;
    size_t baseB = baseA + SEQ;
    size_t baseC = baseB + SEQ;
    size_t baseD = baseC + SEQ;
    P[baseA + t      ] = f2bf(pa0 * invA);
    P[baseA + t + 256] = f2bf(pa1 * invA);
    P[baseA + t + 512] = f2bf(pa2 * invA);
    P[baseA + t + 768] = f2bf(pa3 * invA);
    P[baseB + t      ] = f2bf(pb0 * invB);
    P[baseB + t + 256] = f2bf(pb1 * invB);
    P[baseB + t + 512] = f2bf(pb2 * invB);
    P[baseB + t + 768] = f2bf(pb3 * invB);
    P[baseC + t      ] = f2bf(pc0 * invC);
    P[baseC + t + 256] = f2bf(pc1 * invC);
    P[baseC + t + 512] = f2bf(pc2 * invC);
    P[baseC + t + 768] = f2bf(pc3 * invC);
    P[baseD + t      ] = f2bf(pd0 * invD);
    P[baseD + t + 256] = f2bf(pd1 * invD);
    P[baseD + t + 512] = f2bf(pd2 * invD);
    P[baseD + t + 768] = f2bf(pd3 * invD);
}

// ---------------- Kernel 4: out = P @ V  (bf16 GEMM, 64x64 tile, PAIR-dbuf) ---------
// Pair-dbuf (syncs 8), 64 KB LDS, 2 blocks/CU. XCD-swizzled: batch pinned to
// 2 XCDs (P+VT slices L2-resident). Sum order unchanged -> bit-identical.
__global__ __launch_bounds__(256, 2) void pv_kernel(
    const u16* __restrict__ P, const u16* __restrict__ VT,
    float* __restrict__ out)
{
    __shared__ __attribute__((aligned(16))) u16 lds[32768];   // 64 KB: 2buf x 2tile
    int t = threadIdx.x;
    int l = t & 63, wid = t >> 6;
    int wm = (wid >> 1) * 32, wn = (wid & 1) * 32;
    int lin = (blockIdx.z << 7) + (blockIdx.y << 3) + blockIdx.x;
    int v = (lin & 7) * 64 + (lin >> 3);
    int zb = v >> 7;
    int w_ = v & 127;
    int m0 = (w_ >> 3) * 64, n0 = (w_ & 7) * 64;
    const u16* pA = P + (size_t)zb * SEQ * SEQ + (size_t)m0 * SEQ;
    const u16* pB = VT + (size_t)n0 * 4096 + ((size_t)zb << 10);

    f32x4 acc[2][2] = {};

    auto STAGE = [&](int buf, int kp) {        // stages K-tiles 2kp, 2kp+1
        u16* base = lds + buf * 16384;
        stageR<64>(pA, SEQ,  2 * kp,     base,         t);
        stageR<64>(pB, 4096, 2 * kp,     base + 4096,  t);
        stageR<64>(pA, SEQ,  2 * kp + 1, base + 8192,  t);
        stageR<64>(pB, 4096, 2 * kp + 1, base + 12288, t);
    };
    auto COMPUTE = [&](int buf) {
        #pragma unroll
        for (int half = 0; half < 2; ++half) {
            u16* lA = lds + buf * 16384 + half * 8192;
            u16* lB = lA + 4096;
            #pragma unroll
            for (int kk = 0; kk < 2; ++kk) {
                int sb = (kk << 2) + (l >> 4);
                bf16x8 af[2], bf_[2];
                #pragma unroll
                for (int mf = 0; mf < 2; ++mf)
                    af[mf] = ldfrag(lA, wm + mf * 16 + (l & 15), sb);
                #pragma unroll
                for (int nf = 0; nf < 2; ++nf)
                    bf_[nf] = ldfrag(lB, wn + nf * 16 + (l & 15), sb);
                #pragma unroll
                for (int mf = 0; mf < 2; ++mf)
                    #pragma unroll
                    for (int nf = 0; nf < 2; ++nf)
                        acc[mf][nf] = __builtin_amdgcn_mfma_f32_16x16x32_bf16(af[mf], bf_[nf], acc[mf][nf], 0, 0, 0);
            }
        }
    };

    STAGE(0, 0);
    __syncthreads();
    int cur = 0;
    for (int kp = 0; kp + 1 < 8; ++kp) {
        STAGE(cur ^ 1, kp + 1);
        COMPUTE(cur);
        __syncthreads();
        cur ^= 1;
    }
    COMPUTE(cur);

    int cr = (l >> 4) << 2, cc = l & 15;
    #pragma unroll
    for (int mf = 0; mf < 2; ++mf)
        #pragma unroll
        for (int nf = 0; nf < 2; ++nf)
            #pragma unroll
            for (int r = 0; r < 4; ++r)
                out[((size_t)(zb * SEQ) + m0 + wm + mf * 16 + cr + r) * EMBED
                    + n0 + wn + nf * 16 + cc] = acc[mf][nf][r];
}

extern "C" void kernel_launch(void* const* d_in, const int* in_sizes, int n_in,
                              void* d_out, int out_size, void* d_ws, size_t ws_size,
                              hipStream_t stream) {
    const float* x   = (const float*)d_in[0];
    const float* Wq  = (const float*)d_in[1];
    const float* Wk  = (const float*)d_in[2];
    const float* Wvm = (const float*)d_in[3];
    const float* W1  = (const float*)d_in[4];
    const float* b1  = (const float*)d_in[5];
    const float* w2  = (const float*)d_in[6];
    // d_in[7] = b2: softmax shift-invariant, unused.

    char* ws = (char*)d_ws;
    u16*   AH   = (u16*)(ws + 0);             //   589,824 B  [576][512]
    u16*   AL   = (u16*)(ws + 589824);        //   589,824 B
    u16*   x_hi = (u16*)(ws + 1179648);       // 4,194,304 B  [4096][512]
    u16*   VT   = (u16*)(ws + 5373952);       // 4,194,304 B  [512][4096]
    float* EAt  = (float*)(ws + 9568256);     //   262,144 B  [16][4096]
    float* EBt  = (float*)(ws + 9830400);     //   262,144 B  [16][4096]
    u16*   P    = (u16*)(ws + 10092544);      // 8,388,608 B  [4096][1024]
    float* out  = (float*)d_out;

    hipLaunchKernelGGL(prep_kernel, dim3(2368), dim3(256), 0, stream,
                       Wq, Wk, W1, Wvm, x, AH, AL, x_hi);
    hipLaunchKernelGGL(gemm_kernel, dim3(64, 9), dim3(256), 0, stream,
                       AH, AL, x_hi, b1, VT, EAt, EBt);
    hipLaunchKernelGGL(attn_kernel, dim3(1024), dim3(256), 0, stream,
                       EAt, EBt, w2, P);
    hipLaunchKernelGGL(pv_kernel, dim3(8, 16, 4), dim3(256), 0, stream,
                       P, VT, out);
}

// Round 23
// 53.900 us; speedup vs baseline: 1.0257x; 1.0257x over previous
//
#include <hip/hip_runtime.h>
#include <math.h>
#include <stdint.h>

#define EMBED 512
#define HID 16
#define SEQ 1024

typedef unsigned short u16;
typedef __attribute__((ext_vector_type(8))) __bf16 bf16x8;
typedef __attribute__((ext_vector_type(4))) float f32x4;

__device__ __forceinline__ u16 f2bf(float f) {
    unsigned u = __float_as_uint(f);
    unsigned r = (u + 0x7FFFu + ((u >> 16) & 1u)) >> 16;   // RNE
    return (u16)r;
}
__device__ __forceinline__ float bf2f(u16 h) {
    return __uint_as_float(((unsigned)h) << 16);
}
__device__ __forceinline__ void gload16(const void* g, void* d) {
    __builtin_amdgcn_global_load_lds(
        reinterpret_cast<const __attribute__((address_space(1))) unsigned int*>(
            reinterpret_cast<uintptr_t>(g)),
        reinterpret_cast<__attribute__((address_space(3))) unsigned int*>(
            reinterpret_cast<uintptr_t>(d)),
        16, 0, 0);
}

// ---------------- Kernel 1: prep — fold Wc rows + Wv split + x split ----------------
// A-matrix rows 0..511 = Wv hi/lo; 512..543 = Wc hi/lo; 544..575 = zero pad.
__global__ __launch_bounds__(256) void prep_kernel(
    const float* __restrict__ Wq, const float* __restrict__ Wk,
    const float* __restrict__ W1, const float* __restrict__ Wvm,
    const float* __restrict__ x,
    u16* __restrict__ AH, u16* __restrict__ AL, u16* __restrict__ x_hi)
{
    __shared__ float w1s[EMBED];
    int t = threadIdx.x;
    int blk = blockIdx.x;
    if (blk < 64) {
        int h2 = blk >> 1, half = blk & 1;
        int ab = h2 >> 4, h = h2 & 15;
        const float* Wmat = ab ? Wk : Wq;
        const float* w1row = W1 + (size_t)h * (2 * EMBED) + ab * EMBED;
        for (int f = t; f < EMBED; f += 256) w1s[f] = w1row[f];
        __syncthreads();
        int e0 = (half << 8) + t;
        float acc = 0.f;
        #pragma unroll 16
        for (int f = 0; f < EMBED; ++f)
            acc += w1s[f] * Wmat[(size_t)f * EMBED + e0];
        u16 hi = f2bf(acc);
        AH[(size_t)(512 + h2) * EMBED + e0] = hi;
        AL[(size_t)(512 + h2) * EMBED + e0] = f2bf(acc - bf2f(hi));
        AH[(size_t)(544 + h2) * EMBED + e0] = 0;        // pad rows 544..575
        AL[(size_t)(544 + h2) * EMBED + e0] = 0;
    } else if (blk < 320) {
        int i = (blk - 64) * 256 + t;                   // float4 idx < 65536
        float4 v = ((const float4*)Wvm)[i];
        u16 h0 = f2bf(v.x), h1 = f2bf(v.y), h2 = f2bf(v.z), h3 = f2bf(v.w);
        ((ushort4*)AH)[i] = make_ushort4(h0, h1, h2, h3);
        ((ushort4*)AL)[i] = make_ushort4(f2bf(v.x - bf2f(h0)), f2bf(v.y - bf2f(h1)),
                                         f2bf(v.z - bf2f(h2)), f2bf(v.w - bf2f(h3)));
    } else {
        int i = (blk - 320) * 256 + t;                  // float4 idx < 524288
        float4 v = ((const float4*)x)[i];
        ((ushort4*)x_hi)[i] = make_ushort4(f2bf(v.x), f2bf(v.y), f2bf(v.z), f2bf(v.w));
    }
}

// ---------------- staging helpers (128B-row tiles, XOR swizzle; proven) ----------------
template<int NR>
__device__ __forceinline__ void stageR(const u16* src, int ld, int kt,
                                       u16* ldsb, int t)
{
    int kb0 = kt << 7;
    #pragma unroll
    for (int i = 0; i < NR / 32; ++i) {
        int row  = i * 32 + (t >> 3);
        int colb = (((t & 7) ^ ((t >> 3) & 7)) << 4);
        const char* g = (const char*)src + (size_t)row * ((size_t)ld * 2) + kb0 + colb;
        gload16(g, (char*)ldsb + i * 4096 + ((t >> 6) << 10) + ((t & 63) << 4));
    }
}
__device__ __forceinline__ bf16x8 ldfrag(const u16* ldsb, int r, int s) {
    return *(const bf16x8*)((const char*)ldsb + r * 128 + (((s ^ (r & 7))) << 4));
}

// ---------------- Kernel 2: unified GEMM  [Wv;Wc;pad] x x_hi^T (64x64 tile) ---------
// R19/R21-proven optimum: PAIR-staged single-buffer (2 K-tiles/barrier, 48 KB,
// 3 blocks/CU co-residency — occupancy beats dbuf, confirmed R20/R22), XCD-swizzled.
// m-tiles 0..7 (Wv): single-term bf16; m-tile 8 (Wc): 2-term hi/lo.
__global__ __launch_bounds__(256, 3) void gemm_kernel(
    const u16* __restrict__ AH, const u16* __restrict__ AL,
    const u16* __restrict__ Bh, const float* __restrict__ b1,
    u16* __restrict__ VT, float* __restrict__ EAt, float* __restrict__ EBt)
{
    const float K2 = 2.8853900817779268f;   // 2*log2(e)
    __shared__ __attribute__((aligned(16))) u16 lds[24576];   // 48 KB (2 tiles)
    int t = threadIdx.x;
    int l = t & 63, wid = t >> 6;
    int wm = (wid >> 1) * 32, wn = (wid & 1) * 32;
    // bijective XCD swizzle: 576 = 8 XCD-chunks x 72 (8 n-tiles x 9 m-tiles)
    int lin = blockIdx.y * 64 + blockIdx.x;
    int v = (lin & 7) * 72 + (lin >> 3);
    int mt = v % 9, nt = v / 9;
    int m0 = mt * 64, n0 = nt * 64;
    const u16* pAh = AH + (size_t)m0 * EMBED;
    const u16* pAl = AL + (size_t)m0 * EMBED;
    const u16* pBh = Bh + (size_t)n0 * EMBED;
    f32x4 acc[2][2] = {};
    const bool two = (mt == 8);     // Wc tile: 2-term

    for (int kp = 0; kp < 4; ++kp) {
        stageR<64>(pAh, EMBED, 2 * kp,     lds,         t);
        if (two) stageR<64>(pAl, EMBED, 2 * kp,     lds + 4096,  t);
        stageR<64>(pBh, EMBED, 2 * kp,     lds + 8192,  t);
        stageR<64>(pAh, EMBED, 2 * kp + 1, lds + 12288, t);
        if (two) stageR<64>(pAl, EMBED, 2 * kp + 1, lds + 16384, t);
        stageR<64>(pBh, EMBED, 2 * kp + 1, lds + 20480, t);
        __syncthreads();
        #pragma unroll
        for (int half = 0; half < 2; ++half) {
            u16* lAh = lds + half * 12288;
            u16* lAl = lAh + 4096;
            u16* lB  = lAh + 8192;
            #pragma unroll
            for (int kk = 0; kk < 2; ++kk) {
                int sb = (kk << 2) + (l >> 4);
                bf16x8 ah[2], bh[2];
                #pragma unroll
                for (int mf = 0; mf < 2; ++mf)
                    ah[mf] = ldfrag(lAh, wm + mf * 16 + (l & 15), sb);
                #pragma unroll
                for (int nf = 0; nf < 2; ++nf)
                    bh[nf] = ldfrag(lB, wn + nf * 16 + (l & 15), sb);
                if (two) {
                    bf16x8 al2[2];
                    #pragma unroll
                    for (int mf = 0; mf < 2; ++mf)
                        al2[mf] = ldfrag(lAl, wm + mf * 16 + (l & 15), sb);
                    #pragma unroll
                    for (int mf = 0; mf < 2; ++mf)
                        #pragma unroll
                        for (int nf = 0; nf < 2; ++nf) {
                            acc[mf][nf] = __builtin_amdgcn_mfma_f32_16x16x32_bf16(ah[mf],  bh[nf], acc[mf][nf], 0, 0, 0);
                            acc[mf][nf] = __builtin_amdgcn_mfma_f32_16x16x32_bf16(al2[mf], bh[nf], acc[mf][nf], 0, 0, 0);
                        }
                } else {
                    #pragma unroll
                    for (int mf = 0; mf < 2; ++mf)
                        #pragma unroll
                        for (int nf = 0; nf < 2; ++nf)
                            acc[mf][nf] = __builtin_amdgcn_mfma_f32_16x16x32_bf16(ah[mf], bh[nf], acc[mf][nf], 0, 0, 0);
                }
            }
        }
        __syncthreads();
    }

    int cr = (l >> 4) << 2, cc = l & 15;
    #pragma unroll
    for (int mf = 0; mf < 2; ++mf)
        #pragma unroll
        for (int nf = 0; nf < 2; ++nf)
            #pragma unroll
            for (int r = 0; r < 4; ++r) {
                int gr = m0 + wm + mf * 16 + cr + r;
                int col = n0 + wn + nf * 16 + cc;
                float v2 = acc[mf][nf][r];
                if (gr < 512) {
                    VT[(size_t)gr * 4096 + col] = f2bf(v2);
                } else if (gr < 528) {
                    EAt[(size_t)(gr - 512) * 4096 + col] =
                        __builtin_amdgcn_exp2f(K2 * (v2 + b1[gr - 512]));
                } else if (gr < 544) {
                    EBt[(size_t)(gr - 528) * 4096 + col] =
                        __builtin_amdgcn_exp2f(K2 * v2);
                }
            }
}

// ---------------- Kernel 3: logits + fixed-max softmax -> P (bf16, normalized) -------
// 4 q-rows/block (grid 1024): EB L2 traffic halves. Per-row sum order identical.
__global__ __launch_bounds__(256) void attn_kernel(
    const float* __restrict__ EAt, const float* __restrict__ EBt,
    const float* __restrict__ w2, u16* __restrict__ P)
{
    const float L2E = 1.4426950408889634f;
    __shared__ float redA[4], redB[4], redC[4], redD[4];
    int blk = blockIdx.x;             // 0..1023
    int b = blk >> 8;
    int i0 = (blk & 255) << 2;        // 4 rows per block
    int t = threadIdx.x;
    int gA = (b << 10) + i0;

    float ax[HID], ay[HID], az[HID], aw[HID];
    #pragma unroll
    for (int h = 0; h < HID; ++h) {
        const float* Er = EAt + (size_t)h * 4096 + gA;
        ax[h] = Er[0]; ay[h] = Er[1]; az[h] = Er[2]; aw[h] = Er[3];
    }

    float P1a[8], P2a[8], PSa[8];
    #pragma unroll
    for (int p = 0; p < 8; ++p) {
        float w1 = -2.f * w2[2 * p], w2_ = -2.f * w2[2 * p + 1];
        P1a[p] = w1; P2a[p] = w2_; PSa[p] = w1 + w2_;
    }
    float S0 = 0.f;
    #pragma unroll
    for (int p = 0; p < 8; ++p) S0 += fmaxf(P1a[p], 0.f) + fmaxf(P2a[p], 0.f);

    const float* EBb = EBt + (b << 10);
    float pa0, pa1, pa2, pa3, pb0, pb1, pb2, pb3;
    float pc0, pc1, pc2, pc3, pd0, pd1, pd2, pd3;

#define ROWSUM(S, AV) { \
    _Pragma("unroll") \
    for (int q = 0; q < 4; ++q) { \
        int h0 = q << 2, p0 = q << 1, p1 = p0 + 1; \
        float e1 = AV[h0]*bb[h0], e2 = AV[h0+1]*bb[h0+1]; \
        float e3 = AV[h0+2]*bb[h0+2], e4 = AV[h0+3]*bb[h0+3]; \
        float D12 = fmaf(e1, e2, e1) + (e2 + 1.0f); \
        float N12 = fmaf(P2a[p0], e1, fmaf(P1a[p0], e2, PSa[p0])); \
        float D34 = fmaf(e3, e4, e3) + (e4 + 1.0f); \
        float N34 = fmaf(P2a[p1], e3, fmaf(P1a[p1], e4, PSa[p1])); \
        S = fmaf(fmaf(N12, D34, N34 * D12), __builtin_amdgcn_rcpf(D12 * D34), S); \
    } }

#define DOC(c, PA, PB, PC, PD) { \
    int j = t + (c) * 256; \
    float bb[HID]; \
    _Pragma("unroll") \
    for (int h = 0; h < HID; ++h) bb[h] = EBb[(size_t)h * 4096 + j]; \
    float sA = 0.f, sB = 0.f, sC = 0.f, sD = 0.f; \
    ROWSUM(sA, ax) ROWSUM(sB, ay) ROWSUM(sC, az) ROWSUM(sD, aw) \
    PA = __builtin_amdgcn_exp2f((sA - S0) * L2E); \
    PB = __builtin_amdgcn_exp2f((sB - S0) * L2E); \
    PC = __builtin_amdgcn_exp2f((sC - S0) * L2E); \
    PD = __builtin_amdgcn_exp2f((sD - S0) * L2E); }

    DOC(0, pa0, pb0, pc0, pd0)
    DOC(1, pa1, pb1, pc1, pd1)
    DOC(2, pa2, pb2, pc2, pd2)
    DOC(3, pa3, pb3, pc3, pd3)
#undef DOC
#undef ROWSUM

    float sA = (pa0 + pa1) + (pa2 + pa3);
    float sB = (pb0 + pb1) + (pb2 + pb3);
    float sC = (pc0 + pc1) + (pc2 + pc3);
    float sD = (pd0 + pd1) + (pd2 + pd3);
    #pragma unroll
    for (int o = 32; o > 0; o >>= 1) {
        sA += __shfl_xor(sA, o);
        sB += __shfl_xor(sB, o);
        sC += __shfl_xor(sC, o);
        sD += __shfl_xor(sD, o);
    }
    if ((t & 63) == 0) {
        redA[t >> 6] = sA; redB[t >> 6] = sB;
        redC[t >> 6] = sC; redD[t >> 6] = sD;
    }
    __syncthreads();
    float invA = __fdividef(1.f, (redA[0] + redA[1]) + (redA[2] + redA[3]));
    float invB = __fdividef(1.f, (redB[0] + redB[1]) + (redB[2] + redB[3]));
    float invC = __fdividef(1.f, (redC[0] + redC[1]) + (redC[2] + redC[3]));
    float invD = __fdividef(1.f, (redD[0] + redD[1]) + (redD[2] + redD[3]));

    size_t baseA = ((size_t)(b * SEQ) + i0) * SEQ;
    size_t baseB = baseA + SEQ;
    size_t baseC = baseB + SEQ;
    size_t baseD = baseC + SEQ;
    P[baseA + t      ] = f2bf(pa0 * invA);
    P[baseA + t + 256] = f2bf(pa1 * invA);
    P[baseA + t + 512] = f2bf(pa2 * invA);
    P[baseA + t + 768] = f2bf(pa3 * invA);
    P[baseB + t      ] = f2bf(pb0 * invB);
    P[baseB + t + 256] = f2bf(pb1 * invB);
    P[baseB + t + 512] = f2bf(pb2 * invB);
    P[baseB + t + 768] = f2bf(pb3 * invB);
    P[baseC + t      ] = f2bf(pc0 * invC);
    P[baseC + t + 256] = f2bf(pc1 * invC);
    P[baseC + t + 512] = f2bf(pc2 * invC);
    P[baseC + t + 768] = f2bf(pc3 * invC);
    P[baseD + t      ] = f2bf(pd0 * invD);
    P[baseD + t + 256] = f2bf(pd1 * invD);
    P[baseD + t + 512] = f2bf(pd2 * invD);
    P[baseD + t + 768] = f2bf(pd3 * invD);
}

// ---------------- Kernel 4: out = P @ V  (bf16 GEMM, 64x64 tile, PAIR-dbuf) ---------
// Pair-dbuf (syncs 8), 64 KB LDS; grid 512 = 2 blocks/CU (grid-capped, so dbuf
// costs no occupancy here). XCD-swizzled: batch pinned to 2 XCDs. Bit-identical.
__global__ __launch_bounds__(256, 2) void pv_kernel(
    const u16* __restrict__ P, const u16* __restrict__ VT,
    float* __restrict__ out)
{
    __shared__ __attribute__((aligned(16))) u16 lds[32768];   // 64 KB: 2buf x 2tile
    int t = threadIdx.x;
    int l = t & 63, wid = t >> 6;
    int wm = (wid >> 1) * 32, wn = (wid & 1) * 32;
    int lin = (blockIdx.z << 7) + (blockIdx.y << 3) + blockIdx.x;
    int v = (lin & 7) * 64 + (lin >> 3);
    int zb = v >> 7;
    int w_ = v & 127;
    int m0 = (w_ >> 3) * 64, n0 = (w_ & 7) * 64;
    const u16* pA = P + (size_t)zb * SEQ * SEQ + (size_t)m0 * SEQ;
    const u16* pB = VT + (size_t)n0 * 4096 + ((size_t)zb << 10);

    f32x4 acc[2][2] = {};

    auto STAGE = [&](int buf, int kp) {        // stages K-tiles 2kp, 2kp+1
        u16* base = lds + buf * 16384;
        stageR<64>(pA, SEQ,  2 * kp,     base,         t);
        stageR<64>(pB, 4096, 2 * kp,     base + 4096,  t);
        stageR<64>(pA, SEQ,  2 * kp + 1, base + 8192,  t);
        stageR<64>(pB, 4096, 2 * kp + 1, base + 12288, t);
    };
    auto COMPUTE = [&](int buf) {
        #pragma unroll
        for (int half = 0; half < 2; ++half) {
            u16* lA = lds + buf * 16384 + half * 8192;
            u16* lB = lA + 4096;
            #pragma unroll
            for (int kk = 0; kk < 2; ++kk) {
                int sb = (kk << 2) + (l >> 4);
                bf16x8 af[2], bf_[2];
                #pragma unroll
                for (int mf = 0; mf < 2; ++mf)
                    af[mf] = ldfrag(lA, wm + mf * 16 + (l & 15), sb);
                #pragma unroll
                for (int nf = 0; nf < 2; ++nf)
                    bf_[nf] = ldfrag(lB, wn + nf * 16 + (l & 15), sb);
                #pragma unroll
                for (int mf = 0; mf < 2; ++mf)
                    #pragma unroll
                    for (int nf = 0; nf < 2; ++nf)
                        acc[mf][nf] = __builtin_amdgcn_mfma_f32_16x16x32_bf16(af[mf], bf_[nf], acc[mf][nf], 0, 0, 0);
            }
        }
    };

    STAGE(0, 0);
    __syncthreads();
    int cur = 0;
    for (int kp = 0; kp + 1 < 8; ++kp) {
        STAGE(cur ^ 1, kp + 1);
        COMPUTE(cur);
        __syncthreads();
        cur ^= 1;
    }
    COMPUTE(cur);

    int cr = (l >> 4) << 2, cc = l & 15;
    #pragma unroll
    for (int mf = 0; mf < 2; ++mf)
        #pragma unroll
        for (int nf = 0; nf < 2; ++nf)
            #pragma unroll
            for (int r = 0; r < 4; ++r)
                out[((size_t)(zb * SEQ) + m0 + wm + mf * 16 + cr + r) * EMBED
                    + n0 + wn + nf * 16 + cc] = acc[mf][nf][r];
}

extern "C" void kernel_launch(void* const* d_in, const int* in_sizes, int n_in,
                              void* d_out, int out_size, void* d_ws, size_t ws_size,
                              hipStream_t stream) {
    const float* x   = (const float*)d_in[0];
    const float* Wq  = (const float*)d_in[1];
    const float* Wk  = (const float*)d_in[2];
    const float* Wvm = (const float*)d_in[3];
    const float* W1  = (const float*)d_in[4];
    const float* b1  = (const float*)d_in[5];
    const float* w2  = (const float*)d_in[6];
    // d_in[7] = b2: softmax shift-invariant, unused.

    char* ws = (char*)d_ws;
    u16*   AH   = (u16*)(ws + 0);             //   589,824 B  [576][512]
    u16*   AL   = (u16*)(ws + 589824);        //   589,824 B
    u16*   x_hi = (u16*)(ws + 1179648);       // 4,194,304 B  [4096][512]
    u16*   VT   = (u16*)(ws + 5373952);       // 4,194,304 B  [512][4096]
    float* EAt  = (float*)(ws + 9568256);     //   262,144 B  [16][4096]
    float* EBt  = (float*)(ws + 9830400);     //   262,144 B  [16][4096]
    u16*   P    = (u16*)(ws + 10092544);      // 8,388,608 B  [4096][1024]
    float* out  = (float*)d_out;

    hipLaunchKernelGGL(prep_kernel, dim3(2368), dim3(256), 0, stream,
                       Wq, Wk, W1, Wvm, x, AH, AL, x_hi);
    hipLaunchKernelGGL(gemm_kernel, dim3(64, 9), dim3(256), 0, stream,
                       AH, AL, x_hi, b1, VT, EAt, EBt);
    hipLaunchKernelGGL(attn_kernel, dim3(1024), dim3(256), 0, stream,
                       EAt, EBt, w2, P);
    hipLaunchKernelGGL(pv_kernel, dim3(8, 16, 4), dim3(256), 0, stream,
                       P, VT, out);
}